// Round 1
// baseline (661.082 us; speedup 1.0000x reference)
//
#include <hip/hip_runtime.h>
#include <math.h>

// Problem constants (from reference): B=128, P=128, D=128, N=4096, fp32.
constexpr int BB = 128;
constexpr int PP = 128;
constexpr int DD = 128;
constexpr int NN = 4096;
constexpr float kC = 10.0f;
constexpr float kInvSqrtD = 0.08838834764831845f;  // 1/sqrt(128)

constexpr int NTHR = 512;          // 8 waves
constexpr int NWAVES = NTHR / 64;
constexpr int PT = 16;             // p-rows per block
// Each thread owns two float4 n-blocks: n4 = tid and tid+512 (N/4 = 1024 float4 per row)

__device__ __forceinline__ float4 f4_fma(float a, float4 k, float4 acc) {
    acc.x = fmaf(a, k.x, acc.x);
    acc.y = fmaf(a, k.y, acc.y);
    acc.z = fmaf(a, k.z, acc.z);
    acc.w = fmaf(a, k.w, acc.w);
    return acc;
}

__device__ __forceinline__ float4 f4_clip_mask(float4 s, float4 m) {
    float4 r;
    r.x = kC * tanhf(s.x * kInvSqrtD) + m.x;
    r.y = kC * tanhf(s.y * kInvSqrtD) + m.y;
    r.z = kC * tanhf(s.z * kInvSqrtD) + m.z;
    r.w = kC * tanhf(s.w * kInvSqrtD) + m.w;
    return r;
}

__device__ __forceinline__ float f4_max(float4 s) {
    return fmaxf(fmaxf(s.x, s.y), fmaxf(s.z, s.w));
}

__device__ __forceinline__ float4 f4_expsub(float4 s, float mx) {
    float4 r;
    r.x = __expf(s.x - mx);
    r.y = __expf(s.y - mx);
    r.z = __expf(s.z - mx);
    r.w = __expf(s.w - mx);
    return r;
}

__device__ __forceinline__ float f4_sum(float4 s) {
    return (s.x + s.y) + (s.z + s.w);
}

__device__ __forceinline__ float4 f4_scale(float4 s, float v) {
    s.x *= v; s.y *= v; s.z *= v; s.w *= v;
    return s;
}

__global__ __launch_bounds__(NTHR, 2)
void fused_score_softmax(const float* __restrict__ A,   // [B][P][D]
                         const float* __restrict__ K,   // [B][D][N]
                         const float* __restrict__ M,   // [B][P][N]
                         float* __restrict__ O) {       // [B][P][N]
    __shared__ float At[DD][PT];            // A tile, transposed: At[d][p]  (8 KB)
    __shared__ float redmax[NWAVES][PT];
    __shared__ float redsum[NWAVES][PT];

    // XCD-aware swizzle: all 8 p-tiles of a batch land on the same XCD so K[b]
    // (2 MB) stays resident in that XCD's 4 MB L2.
    const int l = blockIdx.x;
    const int xcd = l & 7;
    const int j = l >> 3;
    const int b = xcd + 8 * (j >> 3);   // bijective: b in [0,128)
    const int pt = j & 7;
    const int p_base = pt * PT;

    const int tid = (int)threadIdx.x;
    const int lane = tid & 63;
    const int wid = tid >> 6;

    // ---- Stage A tile (PT x DD), transposed, into LDS ----
    const float* Ab = A + ((size_t)b * PP + p_base) * DD;
    #pragma unroll
    for (int e = tid; e < PT * DD; e += NTHR) {
        const int p = e >> 7;          // e / DD
        const int d = e & (DD - 1);
        At[d][p] = Ab[e];
    }
    __syncthreads();

    // ---- Matmul: acc[p][j] over d, K streamed from global (L2-resident) ----
    const float4* K4 = (const float4*)(K + (size_t)b * DD * NN);
    float4 acc0[PT], acc1[PT];
    #pragma unroll
    for (int p = 0; p < PT; ++p) {
        acc0[p] = make_float4(0.f, 0.f, 0.f, 0.f);
        acc1[p] = make_float4(0.f, 0.f, 0.f, 0.f);
    }

    float4 k0 = K4[tid];
    float4 k1 = K4[512 + tid];
    for (int d = 0; d < DD; ++d) {
        const int dn = (d + 1) & (DD - 1);        // last iter refetches d=0 (discarded)
        const float4 kn0 = K4[dn * (NN / 4) + tid];
        const float4 kn1 = K4[dn * (NN / 4) + 512 + tid];

        const float4 a0 = *(const float4*)&At[d][0];
        const float4 a1 = *(const float4*)&At[d][4];
        const float4 a2 = *(const float4*)&At[d][8];
        const float4 a3 = *(const float4*)&At[d][12];
        const float av[PT] = {a0.x, a0.y, a0.z, a0.w,
                              a1.x, a1.y, a1.z, a1.w,
                              a2.x, a2.y, a2.z, a2.w,
                              a3.x, a3.y, a3.z, a3.w};
        #pragma unroll
        for (int p = 0; p < PT; ++p) {
            acc0[p] = f4_fma(av[p], k0, acc0[p]);
            acc1[p] = f4_fma(av[p], k1, acc1[p]);
        }
        k0 = kn0;
        k1 = kn1;
    }

    // ---- Pointwise: scale, clip (10*tanh), add mask; per-row partial max ----
    const size_t row_off = ((size_t)b * PP + p_base) * NN;
    const float4* M4 = (const float4*)(M + row_off);
    float4* O4 = (float4*)(O + row_off);

    float mx[PT];
    #pragma unroll
    for (int p = 0; p < PT; ++p) {
        const float4 m0 = M4[p * (NN / 4) + tid];
        const float4 m1 = M4[p * (NN / 4) + 512 + tid];
        acc0[p] = f4_clip_mask(acc0[p], m0);
        acc1[p] = f4_clip_mask(acc1[p], m1);
        mx[p] = fmaxf(f4_max(acc0[p]), f4_max(acc1[p]));
    }

    // wave-level max butterfly (64 lanes)
    #pragma unroll
    for (int p = 0; p < PT; ++p) {
        float m = mx[p];
        #pragma unroll
        for (int off = 32; off > 0; off >>= 1)
            m = fmaxf(m, __shfl_xor(m, off));
        mx[p] = m;
    }
    if (lane == 0) {
        #pragma unroll
        for (int p = 0; p < PT; ++p) redmax[wid][p] = mx[p];
    }
    __syncthreads();
    #pragma unroll
    for (int p = 0; p < PT; ++p) {
        float m = redmax[0][p];
        #pragma unroll
        for (int w = 1; w < NWAVES; ++w) m = fmaxf(m, redmax[w][p]);
        mx[p] = m;
    }

    // ---- exp(s - max), per-row partial sum ----
    float sm[PT];
    #pragma unroll
    for (int p = 0; p < PT; ++p) {
        acc0[p] = f4_expsub(acc0[p], mx[p]);
        acc1[p] = f4_expsub(acc1[p], mx[p]);
        sm[p] = f4_sum(acc0[p]) + f4_sum(acc1[p]);
    }
    #pragma unroll
    for (int p = 0; p < PT; ++p) {
        float s = sm[p];
        #pragma unroll
        for (int off = 32; off > 0; off >>= 1)
            s += __shfl_xor(s, off);
        sm[p] = s;
    }
    if (lane == 0) {
        #pragma unroll
        for (int p = 0; p < PT; ++p) redsum[wid][p] = sm[p];
    }
    __syncthreads();

    // ---- normalize and write ----
    #pragma unroll
    for (int p = 0; p < PT; ++p) {
        float s = redsum[0][p];
        #pragma unroll
        for (int w = 1; w < NWAVES; ++w) s += redsum[w][p];
        const float inv = 1.0f / s;
        O4[p * (NN / 4) + tid] = f4_scale(acc0[p], inv);
        O4[p * (NN / 4) + 512 + tid] = f4_scale(acc1[p], inv);
    }
}

extern "C" void kernel_launch(void* const* d_in, const int* in_sizes, int n_in,
                              void* d_out, int out_size, void* d_ws, size_t ws_size,
                              hipStream_t stream) {
    const float* A = (const float*)d_in[0];   // mh_attn_out [128][128][128]
    const float* K = (const float*)d_in[1];   // single_head_key [128][128][4096]
    const float* M = (const float*)d_in[2];   // mask [128][128][4096]
    float* O = (float*)d_out;                 // probs [128][128][4096]

    const int nblocks = BB * (PP / PT);       // 128 * 8 = 1024
    fused_score_softmax<<<dim3(nblocks), dim3(NTHR), 0, stream>>>(A, K, M, O);
}